// Round 5
// baseline (196.896 us; speedup 1.0000x reference)
//
#include <hip/hip_runtime.h>
#include <hip/hip_bf16.h>
#include <math.h>

#define NN 20000
#define NE 320000
#define BN_EPS 1e-5f
#define CAP 48            // per-node edge-bucket capacity (max in-degree ~40 for this data)
#define CNTP 16           // cnt padding: one counter per 64B

// ---- workspace layout (total ~26.9 MB; identical to R4 which passed) ----
#define MSG_BYTES   (NE * 16 * 4)            // 20,480,000  per-edge messages (non-atomic)
#define ELIST_OFF   MSG_BYTES
#define ELIST_BYTES (NN * CAP * 4)           //  3,840,000  bucketed edge ids
#define CNT_OFF     (ELIST_OFF + ELIST_BYTES)
#define CNT_BYTES   (NN * CNTP * 4)          //  1,280,000  padded in-degree counters
#define BNACC_OFF   (CNT_OFF + CNT_BYTES)    // 128 B BN accumulators
#define Y_OFF       (BNACC_OFF + 128)
// memset region: cntp + bnacc (contiguous)
#define ZERO_OFF    CNT_OFF
#define ZERO_BYTES  (CNT_BYTES + 128)

typedef __bf16 bf16x8 __attribute__((ext_vector_type(8)));
typedef float  f32x4  __attribute__((ext_vector_type(4)));

union BF8 { bf16x8 v; unsigned short us[8]; unsigned int ui[4]; };

// R5: native HW converts (v_cvt_pk_bf16_f32, RNE -- bit-identical to the old integer
// emulation, ~4x fewer VALU ops). m240: scalar casts compile to the packed cvt.
__device__ __forceinline__ unsigned short f2bf(float f) {
    __bf16 h = (__bf16)f;
    return __builtin_bit_cast(unsigned short, h);
}
__device__ __forceinline__ float bf2f(unsigned short s) {
    return (float)__builtin_bit_cast(__bf16, s);
}
__device__ __forceinline__ unsigned int pack2bf(float a, float b) {
    return (unsigned int)f2bf(a) | ((unsigned int)f2bf(b) << 16);
}

// ============================ edge path (+fused self stats) ============================
// R5 (R4 post-mortem: loop is clean of atomics yet time unchanged -> latency-bound at
// 16 waves/CU, LDS-capped occupancy; all pipes <40%):
//   - 512-thread blocks (8 waves) share the SAME 32KB A3sw -> 4 blocks/CU x 8 waves
//     = 32 waves/CU (HW thread cap). VGPR already exactly 64 = the 8-wave/SIMD cap.
//   - waves grid-stride independently over 16-edge groups (no intra-loop syncs)
//   - native bf16 casts cut per-iter VALU ~30%
__global__ __launch_bounds__(512, 8) void edge_kernel(
    const float* __restrict__ h_neigh, const float* __restrict__ efeat,
    const int* __restrict__ src, const int* __restrict__ dst,
    const float* __restrict__ We1, const float* __restrict__ be1,
    const float* __restrict__ We2, const float* __restrict__ be2,
    float* __restrict__ msgb, int* __restrict__ elist,
    int* __restrict__ cntp,
    const float* __restrict__ h_self, const float* __restrict__ Wsf,
    float* __restrict__ y, float* __restrict__ bnacc)
{
    // A-frag-swizzled We2^T: [mb][kb][lane][j]  32 KB, shared by all 8 waves
    __shared__ __align__(16) unsigned short A3sw[16 * 2 * 64 * 8];
    __shared__ float red[8][32];   // self-path block reduction

    const int t = threadIdx.x;

    // ---- init A3sw from We2 (coalesced float4 reads, swizzled b16 writes)
    {
        const float4* W2v = (const float4*)We2;
#pragma unroll
        for (int it = 0; it < 8; it++) {
            int c4 = t + 512 * it;          // 0..4095 float4 chunks
            float4 w = W2v[c4];
            int f = c4 * 4;
            int h = f >> 8, c = f & 255;
            int mb = c >> 4, kb = h >> 5, hh = h & 31, co = c & 15;
            int base = ((mb * 2 + kb) * 64 + (hh >> 3) * 16) * 8 + (hh & 7);
            A3sw[base + (co + 0) * 8] = f2bf(w.x);
            A3sw[base + (co + 1) * 8] = f2bf(w.y);
            A3sw[base + (co + 2) * 8] = f2bf(w.z);
            A3sw[base + (co + 3) * 8] = f2bf(w.w);
        }
    }

    // ---- phase 0: bucket build, fully up front (zero atomics in the compute loop).
    // 320K edges / 524288 threads -> <=1 atomic per thread, TLP-hidden, one-time drain.
    {
        int i = (int)blockIdx.x * 512 + t;
        if (i < NE) {
            int d0 = dst[i];
            int k0 = atomicAdd(&cntp[d0 * CNTP], 1);
            if (k0 < CAP) elist[d0 * CAP + k0] = i;
        }
    }
    __syncthreads();

    const int L = t & 63, wv = t >> 6;
    const int lo16 = L & 15, q = L >> 4;
    const int qc = q & 1;
    const bool qlow = (q < 2);
    const bool qhi1 = ((q >> 1) != 0);   // target-side chunk select

    // ---- We1^T A-frags (hi/lo) in registers, bias in slot k=16
    BF8 w1h[4], w1l[4];
#pragma unroll
    for (int c = 0; c < 4; c++) {
#pragma unroll
        for (int j = 0; j < 8; j++) {
            float w;
            if (q < 2)                 w = We1[(q * 8 + j) * 64 + c * 16 + lo16];
            else if (q == 2 && j == 0) w = be1[c * 16 + lo16];
            else                       w = 0.f;
            unsigned short h = f2bf(w);
            w1h[c].us[j] = h;
            w1l[c].us[j] = f2bf(w - bf2f(h));
        }
    }

    // A-frag of be2^T
    BF8 be2T;
#pragma unroll
    for (int j = 0; j < 8; j++) {
        float bv = be2[(qc * 8 + j) * 16 + lo16];
        be2T.us[j] = qlow ? f2bf(bv) : (unsigned short)0;
    }

    // bpermute source-lane byte addresses (loop-invariant)
    const int addrA = (((q & 1) * 2 + 0) * 16 + lo16) * 4;
    const int addrB = (((q & 1) * 2 + 1) * 16 + lo16) * 4;

    // ---- main loop: each WAVE grid-strides independently over 16-edge groups
    // (A3sw is read-only after the sync; no inter-wave dependency).
    const int NG = NE / 16;                       // 20000 wave-groups
    const int NW = (int)gridDim.x * 8;            // 8192 waves
    for (int g = (int)blockIdx.x * 8 + wv; g < NG; g += NW) {
        int e = g * 16 + lo16;
        int se = src[e];

        float xr[16];
        {
            const float4* xp = (const float4*)(h_neigh + (size_t)se * 16);
#pragma unroll
            for (int k4 = 0; k4 < 4; k4++) {
                float4 a = xp[k4];
                xr[k4*4+0] = a.x; xr[k4*4+1] = a.y; xr[k4*4+2] = a.z; xr[k4*4+3] = a.w;
            }
        }

        // B-frag of ef^T (hi/lo), bias partner 1.0 at (q==2, j==0)
        BF8 a2h, a2l;
        {
            const float4* ep = (const float4*)(efeat + (size_t)e * 16 + qc * 8);
            float4 e0 = ep[0], e1 = ep[1];
            float ev[8] = {e0.x, e0.y, e0.z, e0.w, e1.x, e1.y, e1.z, e1.w};
#pragma unroll
            for (int j = 0; j < 8; j++) {
                if (qlow) {
                    unsigned short h = f2bf(ev[j]);
                    a2h.us[j] = h;
                    a2l.us[j] = f2bf(ev[j] - bf2f(h));
                } else {
                    a2h.us[j] = (q == 2 && j == 0) ? (unsigned short)0x3F80 : (unsigned short)0;
                    a2l.us[j] = 0;
                }
            }
        }

        // stage 2T: ehT chunk c holds rows h = c*16 + q*4 + r, col = edge lo16
        float vch[4][4];
#pragma unroll
        for (int c = 0; c < 4; c++) {
            f32x4 c2 = {0.f, 0.f, 0.f, 0.f};
            c2 = __builtin_amdgcn_mfma_f32_16x16x32_bf16(w1h[c].v, a2h.v, c2, 0, 0, 0);
            c2 = __builtin_amdgcn_mfma_f32_16x16x32_bf16(w1l[c].v, a2h.v, c2, 0, 0, 0);
            c2 = __builtin_amdgcn_mfma_f32_16x16x32_bf16(w1h[c].v, a2l.v, c2, 0, 0, 0);
#pragma unroll
            for (int r = 0; r < 4; r++) vch[c][r] = fmaxf(c2[r], 0.f);
        }

        // pack hi/lo dword pairs
        unsigned int dwH[4][2], dwL[4][2];
#pragma unroll
        for (int c = 0; c < 4; c++) {
#pragma unroll
            for (int d = 0; d < 2; d++) {
                float va = vch[c][2*d], vb = vch[c][2*d+1];
                unsigned short ha = f2bf(va), hb = f2bf(vb);
                dwH[c][d] = (unsigned int)ha | ((unsigned int)hb << 16);
                dwL[c][d] = pack2bf(va - bf2f(ha), vb - bf2f(hb));
            }
        }

        // pulls -> stage-3 B-frags: pull BOTH chunk candidates, select by q>>1
        BF8 b3h[2], b3l[2];
#pragma unroll
        for (int kb = 0; kb < 2; kb++) {
#pragma unroll
            for (int tt = 0; tt < 4; tt++) {
                int d = tt & 1;
                int addr = (tt >> 1) ? addrB : addrA;
                int h0 = __builtin_amdgcn_ds_bpermute(addr, (int)dwH[kb*2+0][d]);
                int h1 = __builtin_amdgcn_ds_bpermute(addr, (int)dwH[kb*2+1][d]);
                int l0 = __builtin_amdgcn_ds_bpermute(addr, (int)dwL[kb*2+0][d]);
                int l1 = __builtin_amdgcn_ds_bpermute(addr, (int)dwL[kb*2+1][d]);
                b3h[kb].ui[tt] = (unsigned int)(qhi1 ? h1 : h0);
                b3l[kb].ui[tt] = (unsigned int)(qhi1 ? l1 : l0);
            }
        }

        // be2 term: msg = be2^T @ x^T
        BF8 xT;
#pragma unroll
        for (int j = 0; j < 8; j++)
            xT.us[j] = qlow ? f2bf(xr[qc * 8 + j]) : (unsigned short)0;
        f32x4 msg = {0.f, 0.f, 0.f, 0.f};
        msg = __builtin_amdgcn_mfma_f32_16x16x32_bf16(be2T.v, xT.v, msg, 0, 0, 0);

        // stage 3: per mb(=i): C = We2^T @ ehT, msg += x[i]*C
#pragma unroll 4
        for (int mb = 0; mb < 16; mb++) {
            bf16x8 a3a = *(const bf16x8*)&A3sw[((mb * 2 + 0) * 64 + L) * 8];
            bf16x8 a3b = *(const bf16x8*)&A3sw[((mb * 2 + 1) * 64 + L) * 8];
            f32x4 acc = {0.f, 0.f, 0.f, 0.f};
            acc = __builtin_amdgcn_mfma_f32_16x16x32_bf16(a3a, b3h[0].v, acc, 0, 0, 0);
            acc = __builtin_amdgcn_mfma_f32_16x16x32_bf16(a3b, b3h[1].v, acc, 0, 0, 0);
            acc = __builtin_amdgcn_mfma_f32_16x16x32_bf16(a3a, b3l[0].v, acc, 0, 0, 0);
            acc = __builtin_amdgcn_mfma_f32_16x16x32_bf16(a3b, b3l[1].v, acc, 0, 0, 0);
            float xm = xr[mb];
            msg[0] += xm * acc[0];
            msg[1] += xm * acc[1];
            msg[2] += xm * acc[2];
            msg[3] += xm * acc[3];
        }

        // ---- emit: unconditional coalesced store (overflow edges just aren't in elist)
        *(float4*)(msgb + (size_t)e * 16 + q * 4) =
            make_float4(msg[0], msg[1], msg[2], msg[3]);
    }

    // ---------------- fused self path (blocks 984..1023: 40 x 512 threads) ----------------
    int sb = (int)blockIdx.x - 984;
    if (sb >= 0) {
        int n = sb * 512 + t;
        bool act = (n < NN);
        float hv[16], yv[16];
        if (act) {
            const float4* h4 = (const float4*)(h_self + (size_t)n * 16);
#pragma unroll
            for (int k = 0; k < 4; k++) {
                float4 a = h4[k];
                hv[4*k+0] = a.x; hv[4*k+1] = a.y; hv[4*k+2] = a.z; hv[4*k+3] = a.w;
            }
        } else {
#pragma unroll
            for (int i = 0; i < 16; i++) hv[i] = 0.f;
        }
#pragma unroll
        for (int o = 0; o < 16; o++) {
            float a = 0.f;
#pragma unroll
            for (int i = 0; i < 16; i++) a += hv[i] * Wsf[i*16 + o];
            yv[o] = a;
        }
        if (act) {
            float4* y4 = (float4*)(y + (size_t)n * 16);
#pragma unroll
            for (int k = 0; k < 4; k++)
                y4[k] = make_float4(yv[4*k+0], yv[4*k+1], yv[4*k+2], yv[4*k+3]);
        }
        int lane = t & 63;
#pragma unroll
        for (int o = 0; o < 16; o++) {
            float a = act ? yv[o] : 0.f;
            float b = act ? yv[o]*yv[o] : 0.f;
#pragma unroll
            for (int off = 32; off > 0; off >>= 1) {
                a += __shfl_down(a, off);
                b += __shfl_down(b, off);
            }
            if (lane == 0) { red[wv][o] = a; red[wv][16 + o] = b; }
        }
        __syncthreads();
        if (t < 32) {
            float s = 0.f;
#pragma unroll
            for (int w = 0; w < 8; w++) s += red[w][t];
            atomicAdd(&bnacc[t], s);
        }
    }
}

// ---- finalize: per-node msg gather-sum + BN + tanh + add + relu + L2-normalize ----
// 4 threads per node; thread c owns components c*4..c*4+3. Per edge the node's 4
// adjacent lanes read a contiguous 64B msg row (coalesced). deg>CAP (never for this
// data): full-scan fallback over dst[] for correctness in general.
__global__ __launch_bounds__(256) void final_kernel(
    const float* __restrict__ msgb, const int* __restrict__ elist,
    const int* __restrict__ cntp, const int* __restrict__ dst,
    const float* __restrict__ y, const float* __restrict__ bnacc,
    const float* __restrict__ gamma, const float* __restrict__ beta,
    float* __restrict__ out)
{
    int tb = blockIdx.x * 256 + threadIdx.x;
    int n = tb >> 2, c = tb & 3;
    if (n >= NN) return;

    int deg = cntp[n * CNTP];
    const float4* m4 = (const float4*)msgb;

    float ax = 0.f, ay = 0.f, az = 0.f, aw = 0.f;
    if (deg <= CAP) {
        const int* el = elist + n * CAP;
        int k = 0;
        for (; k + 4 <= deg; k += 4) {
            int e0 = el[k], e1 = el[k+1], e2 = el[k+2], e3 = el[k+3];
            float4 a0 = m4[(size_t)e0*4 + c];
            float4 a1 = m4[(size_t)e1*4 + c];
            float4 a2 = m4[(size_t)e2*4 + c];
            float4 a3 = m4[(size_t)e3*4 + c];
            ax += (a0.x + a1.x) + (a2.x + a3.x);
            ay += (a0.y + a1.y) + (a2.y + a3.y);
            az += (a0.z + a1.z) + (a2.z + a3.z);
            aw += (a0.w + a1.w) + (a2.w + a3.w);
        }
        for (; k < deg; k++) {
            int e0 = el[k];
            float4 a0 = m4[(size_t)e0*4 + c];
            ax += a0.x; ay += a0.y; az += a0.z; aw += a0.w;
        }
    } else {
        // overflow fallback: scan every edge (correctness insurance; ~never taken)
        for (int e0 = 0; e0 < NE; e0++) {
            if (dst[e0] == n) {
                float4 a0 = m4[(size_t)e0*4 + c];
                ax += a0.x; ay += a0.y; az += a0.z; aw += a0.w;
            }
        }
    }

    float4 yv4 = ((const float4*)y)[(size_t)n * 4 + c];
    float yv[4] = {yv4.x, yv4.y, yv4.z, yv4.w};
    float nb[4] = {ax, ay, az, aw};

    const float inv_n = 1.f / (float)NN;
    float z[4];
    float ss = 0.f;
#pragma unroll
    for (int r = 0; r < 4; r++) {
        int o = c * 4 + r;
        float mu  = bnacc[o] * inv_n;
        float var = bnacc[16 + o] * inv_n - mu * mu;
        float inv = rsqrtf(var + BN_EPS);
        float yy  = (yv[r] - mu) * inv * gamma[o] + beta[o];
        float tt  = tanhf(yy);
        float zz  = fmaxf(tt + nb[r], 0.f);
        z[r] = zz;
        ss += zz * zz;
    }
    // node-wide sum of squares across the 4 owning lanes (quad never crosses a wave)
    ss += __shfl_xor(ss, 1);
    ss += __shfl_xor(ss, 2);
    float nrm = sqrtf(ss);
    if (nrm == 0.f) nrm = 1.f;
    float rr = 1.f / nrm;
    *(float4*)(out + (size_t)n * 16 + c * 4) =
        make_float4(z[0]*rr, z[1]*rr, z[2]*rr, z[3]*rr);
}

extern "C" void kernel_launch(void* const* d_in, const int* in_sizes, int n_in,
                              void* d_out, int out_size, void* d_ws, size_t ws_size,
                              hipStream_t stream) {
    const float* h_neigh = (const float*)d_in[0];
    const float* h_self  = (const float*)d_in[1];
    const float* efeat   = (const float*)d_in[2];
    const int*   src     = (const int*)d_in[3];
    const int*   dst     = (const int*)d_in[4];
    const float* W_self  = (const float*)d_in[5];
    const float* gamma   = (const float*)d_in[6];
    const float* beta    = (const float*)d_in[7];
    const float* We1     = (const float*)d_in[8];
    const float* be1     = (const float*)d_in[9];
    const float* We2     = (const float*)d_in[10];
    const float* be2     = (const float*)d_in[11];
    float* out = (float*)d_out;

    char* ws = (char*)d_ws;
    float* msgb  = (float*)ws;
    int*   elist = (int*)(ws + ELIST_OFF);
    int*   cntp  = (int*)(ws + CNT_OFF);
    float* bnacc = (float*)(ws + BNACC_OFF);
    float* y     = (float*)(ws + Y_OFF);

    // zero padded counters + BN accumulators (ws poisoned 0xAA each call)
    hipMemsetAsync(ws + ZERO_OFF, 0, ZERO_BYTES, stream);

    // 1024 blocks x 512 threads = 4 blocks/CU x 8 waves = 32 waves/CU (HW cap);
    // waves grid-stride over 20000 16-edge groups; blocks 984..1023 also do self path.
    edge_kernel<<<1024, 512, 0, stream>>>(
        h_neigh, efeat, src, dst, We1, be1, We2, be2,
        msgb, elist, cntp,
        h_self, W_self, y, bnacc);
    final_kernel<<<(NN * 4 + 255) / 256, 256, 0, stream>>>(
        msgb, elist, cntp, dst, y, bnacc, gamma, beta, out);
}

// Round 7
// 162.496 us; speedup vs baseline: 1.2117x; 1.2117x over previous
//
#include <hip/hip_runtime.h>
#include <hip/hip_bf16.h>
#include <math.h>

#define NN 20000
#define NE 320000
#define BN_EPS 1e-5f
#define CAP 48            // per-node edge-bucket capacity (max in-degree ~40 for this data)
#define CNTP 16           // cnt padding: one counter per 64B

// ---- workspace layout (total ~26.9 MB; identical to R4 which passed) ----
#define MSG_BYTES   (NE * 16 * 4)            // 20,480,000  per-edge messages (non-atomic)
#define ELIST_OFF   MSG_BYTES
#define ELIST_BYTES (NN * CAP * 4)           //  3,840,000  bucketed edge ids
#define CNT_OFF     (ELIST_OFF + ELIST_BYTES)
#define CNT_BYTES   (NN * CNTP * 4)          //  1,280,000  padded in-degree counters
#define BNACC_OFF   (CNT_OFF + CNT_BYTES)    // 128 B BN accumulators
#define Y_OFF       (BNACC_OFF + 128)
// memset region: cntp + bnacc (contiguous)
#define ZERO_OFF    CNT_OFF
#define ZERO_BYTES  (CNT_BYTES + 128)

typedef __bf16 bf16x8 __attribute__((ext_vector_type(8)));
typedef float  f32x4  __attribute__((ext_vector_type(4)));

union BF8 { bf16x8 v; unsigned short us[8]; unsigned int ui[4]; };

// native HW converts (v_cvt_pk_bf16_f32, RNE -- bit-identical to integer emulation)
__device__ __forceinline__ unsigned short f2bf(float f) {
    __bf16 h = (__bf16)f;
    return __builtin_bit_cast(unsigned short, h);
}
__device__ __forceinline__ float bf2f(unsigned short s) {
    return (float)__builtin_bit_cast(__bf16, s);
}
__device__ __forceinline__ unsigned int pack2bf(float a, float b) {
    return (unsigned int)f2bf(a) | ((unsigned int)f2bf(b) << 16);
}

// ============================ edge path (+fused self stats) ============================
// R7 = R6 resubmitted (R6 container failure had no kernel-side mechanism: the only
// change vs R5-passing was the launch_bounds 2nd arg, i.e. register budget; R2->R3
// precedent says these are infra flakes). Theory unchanged:
//   - R4: loop clean of atomics, all pipes <40% -> latency-bound at 16 waves/CU (LDS cap)
//   - R5: 512-thread blocks reach 72% occupancy but (512,8) forced 64 total regs/wave
//     -> VGPR 32 + ~220MB scratch spill traffic (FETCH 135MB / WRITE 142MB)
//   - R7: (512,4) = 128-reg/wave budget (same as R0-R4 which compiled spill-free at 64);
//     LDS limit (33.8KB x 4 = 135KB) and VGPR limit (512/64) BOTH land at 32 waves/CU
__global__ __launch_bounds__(512, 4) void edge_kernel(
    const float* __restrict__ h_neigh, const float* __restrict__ efeat,
    const int* __restrict__ src, const int* __restrict__ dst,
    const float* __restrict__ We1, const float* __restrict__ be1,
    const float* __restrict__ We2, const float* __restrict__ be2,
    float* __restrict__ msgb, int* __restrict__ elist,
    int* __restrict__ cntp,
    const float* __restrict__ h_self, const float* __restrict__ Wsf,
    float* __restrict__ y, float* __restrict__ bnacc)
{
    // A-frag-swizzled We2^T: [mb][kb][lane][j]  32 KB, shared by all 8 waves
    __shared__ __align__(16) unsigned short A3sw[16 * 2 * 64 * 8];
    __shared__ float red[8][32];   // self-path block reduction

    const int t = threadIdx.x;

    // ---- init A3sw from We2 (coalesced float4 reads, swizzled b16 writes)
    {
        const float4* W2v = (const float4*)We2;
#pragma unroll
        for (int it = 0; it < 8; it++) {
            int c4 = t + 512 * it;          // 0..4095 float4 chunks
            float4 w = W2v[c4];
            int f = c4 * 4;
            int h = f >> 8, c = f & 255;
            int mb = c >> 4, kb = h >> 5, hh = h & 31, co = c & 15;
            int base = ((mb * 2 + kb) * 64 + (hh >> 3) * 16) * 8 + (hh & 7);
            A3sw[base + (co + 0) * 8] = f2bf(w.x);
            A3sw[base + (co + 1) * 8] = f2bf(w.y);
            A3sw[base + (co + 2) * 8] = f2bf(w.z);
            A3sw[base + (co + 3) * 8] = f2bf(w.w);
        }
    }

    // ---- phase 0: bucket build, fully up front (zero atomics in the compute loop).
    // 320K edges / 524288 threads -> <=1 atomic per thread, TLP-hidden, one-time drain.
    {
        int i = (int)blockIdx.x * 512 + t;
        if (i < NE) {
            int d0 = dst[i];
            int k0 = atomicAdd(&cntp[d0 * CNTP], 1);
            if (k0 < CAP) elist[d0 * CAP + k0] = i;
        }
    }
    __syncthreads();

    const int L = t & 63, wv = t >> 6;
    const int lo16 = L & 15, q = L >> 4;
    const int qc = q & 1;
    const bool qlow = (q < 2);
    const bool qhi1 = ((q >> 1) != 0);   // target-side chunk select

    // ---- We1^T A-frags (hi/lo) in registers, bias in slot k=16
    BF8 w1h[4], w1l[4];
#pragma unroll
    for (int c = 0; c < 4; c++) {
#pragma unroll
        for (int j = 0; j < 8; j++) {
            float w;
            if (q < 2)                 w = We1[(q * 8 + j) * 64 + c * 16 + lo16];
            else if (q == 2 && j == 0) w = be1[c * 16 + lo16];
            else                       w = 0.f;
            unsigned short h = f2bf(w);
            w1h[c].us[j] = h;
            w1l[c].us[j] = f2bf(w - bf2f(h));
        }
    }

    // A-frag of be2^T
    BF8 be2T;
#pragma unroll
    for (int j = 0; j < 8; j++) {
        float bv = be2[(qc * 8 + j) * 16 + lo16];
        be2T.us[j] = qlow ? f2bf(bv) : (unsigned short)0;
    }

    // bpermute source-lane byte addresses (loop-invariant)
    const int addrA = (((q & 1) * 2 + 0) * 16 + lo16) * 4;
    const int addrB = (((q & 1) * 2 + 1) * 16 + lo16) * 4;

    // ---- main loop: each WAVE grid-strides independently over 16-edge groups
    // (A3sw is read-only after the sync; no inter-wave dependency).
    const int NG = NE / 16;                       // 20000 wave-groups
    const int NW = (int)gridDim.x * 8;            // 8192 waves
    for (int g = (int)blockIdx.x * 8 + wv; g < NG; g += NW) {
        int e = g * 16 + lo16;
        int se = src[e];

        float xr[16];
        {
            const float4* xp = (const float4*)(h_neigh + (size_t)se * 16);
#pragma unroll
            for (int k4 = 0; k4 < 4; k4++) {
                float4 a = xp[k4];
                xr[k4*4+0] = a.x; xr[k4*4+1] = a.y; xr[k4*4+2] = a.z; xr[k4*4+3] = a.w;
            }
        }

        // B-frag of ef^T (hi/lo), bias partner 1.0 at (q==2, j==0)
        BF8 a2h, a2l;
        {
            const float4* ep = (const float4*)(efeat + (size_t)e * 16 + qc * 8);
            float4 e0 = ep[0], e1 = ep[1];
            float ev[8] = {e0.x, e0.y, e0.z, e0.w, e1.x, e1.y, e1.z, e1.w};
#pragma unroll
            for (int j = 0; j < 8; j++) {
                if (qlow) {
                    unsigned short h = f2bf(ev[j]);
                    a2h.us[j] = h;
                    a2l.us[j] = f2bf(ev[j] - bf2f(h));
                } else {
                    a2h.us[j] = (q == 2 && j == 0) ? (unsigned short)0x3F80 : (unsigned short)0;
                    a2l.us[j] = 0;
                }
            }
        }

        // stage 2T: ehT chunk c holds rows h = c*16 + q*4 + r, col = edge lo16
        float vch[4][4];
#pragma unroll
        for (int c = 0; c < 4; c++) {
            f32x4 c2 = {0.f, 0.f, 0.f, 0.f};
            c2 = __builtin_amdgcn_mfma_f32_16x16x32_bf16(w1h[c].v, a2h.v, c2, 0, 0, 0);
            c2 = __builtin_amdgcn_mfma_f32_16x16x32_bf16(w1l[c].v, a2h.v, c2, 0, 0, 0);
            c2 = __builtin_amdgcn_mfma_f32_16x16x32_bf16(w1h[c].v, a2l.v, c2, 0, 0, 0);
#pragma unroll
            for (int r = 0; r < 4; r++) vch[c][r] = fmaxf(c2[r], 0.f);
        }

        // pack hi/lo dword pairs
        unsigned int dwH[4][2], dwL[4][2];
#pragma unroll
        for (int c = 0; c < 4; c++) {
#pragma unroll
            for (int d = 0; d < 2; d++) {
                float va = vch[c][2*d], vb = vch[c][2*d+1];
                unsigned short ha = f2bf(va), hb = f2bf(vb);
                dwH[c][d] = (unsigned int)ha | ((unsigned int)hb << 16);
                dwL[c][d] = pack2bf(va - bf2f(ha), vb - bf2f(hb));
            }
        }

        // pulls -> stage-3 B-frags: pull BOTH chunk candidates, select by q>>1
        BF8 b3h[2], b3l[2];
#pragma unroll
        for (int kb = 0; kb < 2; kb++) {
#pragma unroll
            for (int tt = 0; tt < 4; tt++) {
                int d = tt & 1;
                int addr = (tt >> 1) ? addrB : addrA;
                int h0 = __builtin_amdgcn_ds_bpermute(addr, (int)dwH[kb*2+0][d]);
                int h1 = __builtin_amdgcn_ds_bpermute(addr, (int)dwH[kb*2+1][d]);
                int l0 = __builtin_amdgcn_ds_bpermute(addr, (int)dwL[kb*2+0][d]);
                int l1 = __builtin_amdgcn_ds_bpermute(addr, (int)dwL[kb*2+1][d]);
                b3h[kb].ui[tt] = (unsigned int)(qhi1 ? h1 : h0);
                b3l[kb].ui[tt] = (unsigned int)(qhi1 ? l1 : l0);
            }
        }

        // be2 term: msg = be2^T @ x^T
        BF8 xT;
#pragma unroll
        for (int j = 0; j < 8; j++)
            xT.us[j] = qlow ? f2bf(xr[qc * 8 + j]) : (unsigned short)0;
        f32x4 msg = {0.f, 0.f, 0.f, 0.f};
        msg = __builtin_amdgcn_mfma_f32_16x16x32_bf16(be2T.v, xT.v, msg, 0, 0, 0);

        // stage 3: per mb(=i): C = We2^T @ ehT, msg += x[i]*C
#pragma unroll 4
        for (int mb = 0; mb < 16; mb++) {
            bf16x8 a3a = *(const bf16x8*)&A3sw[((mb * 2 + 0) * 64 + L) * 8];
            bf16x8 a3b = *(const bf16x8*)&A3sw[((mb * 2 + 1) * 64 + L) * 8];
            f32x4 acc = {0.f, 0.f, 0.f, 0.f};
            acc = __builtin_amdgcn_mfma_f32_16x16x32_bf16(a3a, b3h[0].v, acc, 0, 0, 0);
            acc = __builtin_amdgcn_mfma_f32_16x16x32_bf16(a3b, b3h[1].v, acc, 0, 0, 0);
            acc = __builtin_amdgcn_mfma_f32_16x16x32_bf16(a3a, b3l[0].v, acc, 0, 0, 0);
            acc = __builtin_amdgcn_mfma_f32_16x16x32_bf16(a3b, b3l[1].v, acc, 0, 0, 0);
            float xm = xr[mb];
            msg[0] += xm * acc[0];
            msg[1] += xm * acc[1];
            msg[2] += xm * acc[2];
            msg[3] += xm * acc[3];
        }

        // ---- emit: unconditional coalesced store (overflow edges just aren't in elist)
        *(float4*)(msgb + (size_t)e * 16 + q * 4) =
            make_float4(msg[0], msg[1], msg[2], msg[3]);
    }

    // ---------------- fused self path (blocks 984..1023: 40 x 512 threads) ----------------
    int sb = (int)blockIdx.x - 984;
    if (sb >= 0) {
        int n = sb * 512 + t;
        bool act = (n < NN);
        float hv[16], yv[16];
        if (act) {
            const float4* h4 = (const float4*)(h_self + (size_t)n * 16);
#pragma unroll
            for (int k = 0; k < 4; k++) {
                float4 a = h4[k];
                hv[4*k+0] = a.x; hv[4*k+1] = a.y; hv[4*k+2] = a.z; hv[4*k+3] = a.w;
            }
        } else {
#pragma unroll
            for (int i = 0; i < 16; i++) hv[i] = 0.f;
        }
#pragma unroll
        for (int o = 0; o < 16; o++) {
            float a = 0.f;
#pragma unroll
            for (int i = 0; i < 16; i++) a += hv[i] * Wsf[i*16 + o];
            yv[o] = a;
        }
        if (act) {
            float4* y4 = (float4*)(y + (size_t)n * 16);
#pragma unroll
            for (int k = 0; k < 4; k++)
                y4[k] = make_float4(yv[4*k+0], yv[4*k+1], yv[4*k+2], yv[4*k+3]);
        }
        int lane = t & 63;
#pragma unroll
        for (int o = 0; o < 16; o++) {
            float a = act ? yv[o] : 0.f;
            float b = act ? yv[o]*yv[o] : 0.f;
#pragma unroll
            for (int off = 32; off > 0; off >>= 1) {
                a += __shfl_down(a, off);
                b += __shfl_down(b, off);
            }
            if (lane == 0) { red[wv][o] = a; red[wv][16 + o] = b; }
        }
        __syncthreads();
        if (t < 32) {
            float s = 0.f;
#pragma unroll
            for (int w = 0; w < 8; w++) s += red[w][t];
            atomicAdd(&bnacc[t], s);
        }
    }
}

// ---- finalize: per-node msg gather-sum + BN + tanh + add + relu + L2-normalize ----
// 4 threads per node; thread c owns components c*4..c*4+3. Per edge the node's 4
// adjacent lanes read a contiguous 64B msg row (coalesced). deg>CAP (never for this
// data): full-scan fallback over dst[] for correctness in general.
__global__ __launch_bounds__(256) void final_kernel(
    const float* __restrict__ msgb, const int* __restrict__ elist,
    const int* __restrict__ cntp, const int* __restrict__ dst,
    const float* __restrict__ y, const float* __restrict__ bnacc,
    const float* __restrict__ gamma, const float* __restrict__ beta,
    float* __restrict__ out)
{
    int tb = blockIdx.x * 256 + threadIdx.x;
    int n = tb >> 2, c = tb & 3;
    if (n >= NN) return;

    int deg = cntp[n * CNTP];
    const float4* m4 = (const float4*)msgb;

    float ax = 0.f, ay = 0.f, az = 0.f, aw = 0.f;
    if (deg <= CAP) {
        const int* el = elist + n * CAP;
        int k = 0;
        for (; k + 4 <= deg; k += 4) {
            int e0 = el[k], e1 = el[k+1], e2 = el[k+2], e3 = el[k+3];
            float4 a0 = m4[(size_t)e0*4 + c];
            float4 a1 = m4[(size_t)e1*4 + c];
            float4 a2 = m4[(size_t)e2*4 + c];
            float4 a3 = m4[(size_t)e3*4 + c];
            ax += (a0.x + a1.x) + (a2.x + a3.x);
            ay += (a0.y + a1.y) + (a2.y + a3.y);
            az += (a0.z + a1.z) + (a2.z + a3.z);
            aw += (a0.w + a1.w) + (a2.w + a3.w);
        }
        for (; k < deg; k++) {
            int e0 = el[k];
            float4 a0 = m4[(size_t)e0*4 + c];
            ax += a0.x; ay += a0.y; az += a0.z; aw += a0.w;
        }
    } else {
        // overflow fallback: scan every edge (correctness insurance; ~never taken)
        for (int e0 = 0; e0 < NE; e0++) {
            if (dst[e0] == n) {
                float4 a0 = m4[(size_t)e0*4 + c];
                ax += a0.x; ay += a0.y; az += a0.z; aw += a0.w;
            }
        }
    }

    float4 yv4 = ((const float4*)y)[(size_t)n * 4 + c];
    float yv[4] = {yv4.x, yv4.y, yv4.z, yv4.w};
    float nb[4] = {ax, ay, az, aw};

    const float inv_n = 1.f / (float)NN;
    float z[4];
    float ss = 0.f;
#pragma unroll
    for (int r = 0; r < 4; r++) {
        int o = c * 4 + r;
        float mu  = bnacc[o] * inv_n;
        float var = bnacc[16 + o] * inv_n - mu * mu;
        float inv = rsqrtf(var + BN_EPS);
        float yy  = (yv[r] - mu) * inv * gamma[o] + beta[o];
        float tt  = tanhf(yy);
        float zz  = fmaxf(tt + nb[r], 0.f);
        z[r] = zz;
        ss += zz * zz;
    }
    // node-wide sum of squares across the 4 owning lanes (quad never crosses a wave)
    ss += __shfl_xor(ss, 1);
    ss += __shfl_xor(ss, 2);
    float nrm = sqrtf(ss);
    if (nrm == 0.f) nrm = 1.f;
    float rr = 1.f / nrm;
    *(float4*)(out + (size_t)n * 16 + c * 4) =
        make_float4(z[0]*rr, z[1]*rr, z[2]*rr, z[3]*rr);
}

extern "C" void kernel_launch(void* const* d_in, const int* in_sizes, int n_in,
                              void* d_out, int out_size, void* d_ws, size_t ws_size,
                              hipStream_t stream) {
    const float* h_neigh = (const float*)d_in[0];
    const float* h_self  = (const float*)d_in[1];
    const float* efeat   = (const float*)d_in[2];
    const int*   src     = (const int*)d_in[3];
    const int*   dst     = (const int*)d_in[4];
    const float* W_self  = (const float*)d_in[5];
    const float* gamma   = (const float*)d_in[6];
    const float* beta    = (const float*)d_in[7];
    const float* We1     = (const float*)d_in[8];
    const float* be1     = (const float*)d_in[9];
    const float* We2     = (const float*)d_in[10];
    const float* be2     = (const float*)d_in[11];
    float* out = (float*)d_out;

    char* ws = (char*)d_ws;
    float* msgb  = (float*)ws;
    int*   elist = (int*)(ws + ELIST_OFF);
    int*   cntp  = (int*)(ws + CNT_OFF);
    float* bnacc = (float*)(ws + BNACC_OFF);
    float* y     = (float*)(ws + Y_OFF);

    // zero padded counters + BN accumulators (ws poisoned 0xAA each call)
    hipMemsetAsync(ws + ZERO_OFF, 0, ZERO_BYTES, stream);

    // 1024 blocks x 512 threads; LDS 33.8KB -> 4 blocks/CU; VGPR budget 128/wave
    // (launch_bounds min 4 waves/EU) -> spill-free at the loop's ~64, HW occupancy
    // settles at min(LDS 32 w/CU, VGPR 512/used) -- 32 waves/CU if VGPR stays 64.
    edge_kernel<<<1024, 512, 0, stream>>>(
        h_neigh, efeat, src, dst, We1, be1, We2, be2,
        msgb, elist, cntp,
        h_self, W_self, y, bnacc);
    final_kernel<<<(NN * 4 + 255) / 256, 256, 0, stream>>>(
        msgb, elist, cntp, dst, y, bnacc, gamma, beta, out);
}

// Round 8
// 148.489 us; speedup vs baseline: 1.3260x; 1.0943x over previous
//
#include <hip/hip_runtime.h>
#include <hip/hip_bf16.h>
#include <math.h>

#define NN 20000
#define NE 320000
#define BN_EPS 1e-5f
#define CAP 48            // per-node edge-bucket capacity (max in-degree ~40 for this data)
#define CNTP 16           // cnt padding: one counter per 64B

// ---- workspace layout (total ~26.9 MB; identical to R4 which passed) ----
#define MSG_BYTES   (NE * 16 * 4)            // 20,480,000  per-edge messages (non-atomic)
#define ELIST_OFF   MSG_BYTES
#define ELIST_BYTES (NN * CAP * 4)           //  3,840,000  bucketed edge ids
#define CNT_OFF     (ELIST_OFF + ELIST_BYTES)
#define CNT_BYTES   (NN * CNTP * 4)          //  1,280,000  padded in-degree counters
#define BNACC_OFF   (CNT_OFF + CNT_BYTES)    // 128 B BN accumulators
#define Y_OFF       (BNACC_OFF + 128)
// memset region: cntp + bnacc (contiguous)
#define ZERO_OFF    CNT_OFF
#define ZERO_BYTES  (CNT_BYTES + 128)

typedef _Float16 f16x8 __attribute__((ext_vector_type(8)));
typedef float    f32x4 __attribute__((ext_vector_type(4)));

union H8 { f16x8 v; unsigned short us[8]; unsigned int ui[4]; };

// native fp16 converts (v_cvt_f16_f32, RNE)
__device__ __forceinline__ unsigned short f2h(float f) {
    _Float16 h = (_Float16)f;
    return __builtin_bit_cast(unsigned short, h);
}
__device__ __forceinline__ unsigned int pack2h(float a, float b) {
    return (unsigned int)f2h(a) | ((unsigned int)f2h(b) << 16);
}

// ============================ edge path (+fused self stats) ============================
// R8 (R7 post-mortem: doubling waves/CU made it WORSE -> per-CU shared pipe = LDS is the
// bound, ~55-60% of wall: 64 DS ops/group/wave, SQ_LDS_BANK_CONFLICT 9.14M constant).
// Attack = cut DS+VALU volume, keep the proven 256-thread/1024-block shell:
//   - ENTIRE edge-MLP path in single fp16 (rel err 2.4e-4 < the old single-bf16 A3 at
//     2e-3 -> absmax should IMPROVE ~3x) -- removes the hi/lo split:
//     bpermutes 32->16, MFMAs 77->34, pack VALU halved
//   - A-frags for mb 0-3 hoisted to registers (loop-invariant): ds_read_b128 32->24
//   - net DS per group: 64 -> 40 ops
__global__ __launch_bounds__(256, 4) void edge_kernel(
    const float* __restrict__ h_neigh, const float* __restrict__ efeat,
    const int* __restrict__ src, const int* __restrict__ dst,
    const float* __restrict__ We1, const float* __restrict__ be1,
    const float* __restrict__ We2, const float* __restrict__ be2,
    float* __restrict__ msgb, int* __restrict__ elist,
    int* __restrict__ cntp,
    const float* __restrict__ h_self, const float* __restrict__ Wsf,
    float* __restrict__ y, float* __restrict__ bnacc)
{
    // A-frag-swizzled We2^T (fp16): [mb][kb][lane][j]  32 KB
    __shared__ __align__(16) unsigned short A3sw[16 * 2 * 64 * 8];
    __shared__ float red[4][32];   // self-path block reduction

    const int t = threadIdx.x;

    // ---- init A3sw from We2 (coalesced float4 reads, swizzled f16 writes)
    {
        const float4* W2v = (const float4*)We2;
#pragma unroll
        for (int it = 0; it < 16; it++) {
            int c4 = t + 256 * it;          // 0..4095 float4 chunks
            float4 w = W2v[c4];
            int f = c4 * 4;
            int h = f >> 8, c = f & 255;
            int mb = c >> 4, kb = h >> 5, hh = h & 31, co = c & 15;
            int base = ((mb * 2 + kb) * 64 + (hh >> 3) * 16) * 8 + (hh & 7);
            A3sw[base + (co + 0) * 8] = f2h(w.x);
            A3sw[base + (co + 1) * 8] = f2h(w.y);
            A3sw[base + (co + 2) * 8] = f2h(w.z);
            A3sw[base + (co + 3) * 8] = f2h(w.w);
        }
    }

    // ---- phase 0: bucket build, fully up front (zero atomics in the compute loop)
    for (int i = (int)blockIdx.x * 256 + t; i < NE; i += (int)gridDim.x * 256) {
        int d0 = dst[i];
        int k0 = atomicAdd(&cntp[d0 * CNTP], 1);
        if (k0 < CAP) elist[d0 * CAP + k0] = i;
    }
    __syncthreads();

    const int L = t & 63, wv = t >> 6;
    const int lo16 = L & 15, q = L >> 4;
    const int qc = q & 1;
    const bool qlow = (q < 2);
    const bool qhi1 = ((q >> 1) != 0);   // target-side chunk select

    // ---- hoisted A-frags for mb 0..3 (loop-invariant, 32 VGPRs)
    H8 a3r[4][2];
#pragma unroll
    for (int mb = 0; mb < 4; mb++) {
        a3r[mb][0].v = *(const f16x8*)&A3sw[((mb * 2 + 0) * 64 + L) * 8];
        a3r[mb][1].v = *(const f16x8*)&A3sw[((mb * 2 + 1) * 64 + L) * 8];
    }

    // ---- We1^T A-frag (fp16 single), bias in slot k=16
    H8 w1[4];
#pragma unroll
    for (int c = 0; c < 4; c++) {
#pragma unroll
        for (int j = 0; j < 8; j++) {
            float w;
            if (q < 2)                 w = We1[(q * 8 + j) * 64 + c * 16 + lo16];
            else if (q == 2 && j == 0) w = be1[c * 16 + lo16];
            else                       w = 0.f;
            w1[c].us[j] = f2h(w);
        }
    }

    // A-frag of be2^T (fp16)
    H8 be2T;
#pragma unroll
    for (int j = 0; j < 8; j++) {
        float bv = be2[(qc * 8 + j) * 16 + lo16];
        be2T.us[j] = qlow ? f2h(bv) : (unsigned short)0;
    }

    // bpermute source-lane byte addresses (loop-invariant)
    const int addrA = (((q & 1) * 2 + 0) * 16 + lo16) * 4;
    const int addrB = (((q & 1) * 2 + 1) * 16 + lo16) * 4;

    const int NT = NE / 64;
    int bt = blockIdx.x;
    {
        // ---- pipeline prologue: tile 0 src
        int e = bt * 64 + wv * 16 + lo16;
        int se = src[e];

        while (true) {
            // ---- fire NEXT tile's src load (gather address ready one iter ahead)
            int btn = bt + gridDim.x;
            bool hn = btn < NT;
            int en = 0, sen = 0;
            if (hn) {
                en = btn * 64 + wv * 16 + lo16;
                sen = src[en];
            }

            float xr[16];
            {
                const float4* xp = (const float4*)(h_neigh + (size_t)se * 16);
#pragma unroll
                for (int k4 = 0; k4 < 4; k4++) {
                    float4 a = xp[k4];
                    xr[k4*4+0] = a.x; xr[k4*4+1] = a.y; xr[k4*4+2] = a.z; xr[k4*4+3] = a.w;
                }
            }

            // B-frag of ef^T (fp16 single), bias partner 1.0 at (q==2, j==0)
            H8 a2;
            {
                const float4* ep = (const float4*)(efeat + (size_t)e * 16 + qc * 8);
                float4 e0 = ep[0], e1 = ep[1];
                float ev[8] = {e0.x, e0.y, e0.z, e0.w, e1.x, e1.y, e1.z, e1.w};
#pragma unroll
                for (int j = 0; j < 8; j++) {
                    if (qlow) {
                        a2.us[j] = f2h(ev[j]);
                    } else {
                        a2.us[j] = (q == 2 && j == 0) ? (unsigned short)0x3C00 : (unsigned short)0;
                    }
                }
            }

            // stage 2T (1 MFMA/chunk): ehT chunk c holds rows h = c*16 + q*4 + r
            float vch[4][4];
#pragma unroll
            for (int c = 0; c < 4; c++) {
                f32x4 c2 = {0.f, 0.f, 0.f, 0.f};
                c2 = __builtin_amdgcn_mfma_f32_16x16x32_f16(w1[c].v, a2.v, c2, 0, 0, 0);
#pragma unroll
                for (int r = 0; r < 4; r++) vch[c][r] = fmaxf(c2[r], 0.f);
            }

            // pack fp16 dword pairs
            unsigned int dw[4][2];
#pragma unroll
            for (int c = 0; c < 4; c++) {
#pragma unroll
                for (int d = 0; d < 2; d++)
                    dw[c][d] = pack2h(vch[c][2*d], vch[c][2*d+1]);
            }

            // pulls -> stage-3 B-frags: pull BOTH chunk candidates, select by q>>1
            H8 b3[2];
#pragma unroll
            for (int kb = 0; kb < 2; kb++) {
#pragma unroll
                for (int tt = 0; tt < 4; tt++) {
                    int d = tt & 1;
                    int addr = (tt >> 1) ? addrB : addrA;
                    int h0 = __builtin_amdgcn_ds_bpermute(addr, (int)dw[kb*2+0][d]);
                    int h1 = __builtin_amdgcn_ds_bpermute(addr, (int)dw[kb*2+1][d]);
                    b3[kb].ui[tt] = (unsigned int)(qhi1 ? h1 : h0);
                }
            }

            // be2 term: msg = be2^T @ x^T
            H8 xT;
#pragma unroll
            for (int j = 0; j < 8; j++)
                xT.us[j] = qlow ? f2h(xr[qc * 8 + j]) : (unsigned short)0;
            f32x4 msg = {0.f, 0.f, 0.f, 0.f};
            msg = __builtin_amdgcn_mfma_f32_16x16x32_f16(be2T.v, xT.v, msg, 0, 0, 0);

            // stage 3: per mb(=i): C = We2^T @ ehT, msg += x[i]*C
            // mb 0..3 from hoisted registers (static indexing)
#pragma unroll
            for (int mb = 0; mb < 4; mb++) {
                f32x4 acc = {0.f, 0.f, 0.f, 0.f};
                acc = __builtin_amdgcn_mfma_f32_16x16x32_f16(a3r[mb][0].v, b3[0].v, acc, 0, 0, 0);
                acc = __builtin_amdgcn_mfma_f32_16x16x32_f16(a3r[mb][1].v, b3[1].v, acc, 0, 0, 0);
                float xm = xr[mb];
                msg[0] += xm * acc[0];
                msg[1] += xm * acc[1];
                msg[2] += xm * acc[2];
                msg[3] += xm * acc[3];
            }
            // mb 4..15 from LDS
#pragma unroll 4
            for (int mb = 4; mb < 16; mb++) {
                f16x8 a3a = *(const f16x8*)&A3sw[((mb * 2 + 0) * 64 + L) * 8];
                f16x8 a3b = *(const f16x8*)&A3sw[((mb * 2 + 1) * 64 + L) * 8];
                f32x4 acc = {0.f, 0.f, 0.f, 0.f};
                acc = __builtin_amdgcn_mfma_f32_16x16x32_f16(a3a, b3[0].v, acc, 0, 0, 0);
                acc = __builtin_amdgcn_mfma_f32_16x16x32_f16(a3b, b3[1].v, acc, 0, 0, 0);
                float xm = xr[mb];
                msg[0] += xm * acc[0];
                msg[1] += xm * acc[1];
                msg[2] += xm * acc[2];
                msg[3] += xm * acc[3];
            }

            // ---- emit: unconditional coalesced store (overflow edges just aren't in elist)
            *(float4*)(msgb + (size_t)e * 16 + q * 4) =
                make_float4(msg[0], msg[1], msg[2], msg[3]);

            if (!hn) break;
            bt = btn; e = en; se = sen;
        }
    }

    // ---------------- fused self path (blocks 945..1023) ----------------
    int sb = (int)blockIdx.x - 945;
    if (sb >= 0 && sb < 79) {
        int n = sb * 256 + t;
        bool act = (n < NN);
        float hv[16], yv[16];
        if (act) {
            const float4* h4 = (const float4*)(h_self + (size_t)n * 16);
#pragma unroll
            for (int k = 0; k < 4; k++) {
                float4 a = h4[k];
                hv[4*k+0] = a.x; hv[4*k+1] = a.y; hv[4*k+2] = a.z; hv[4*k+3] = a.w;
            }
        } else {
#pragma unroll
            for (int i = 0; i < 16; i++) hv[i] = 0.f;
        }
#pragma unroll
        for (int o = 0; o < 16; o++) {
            float a = 0.f;
#pragma unroll
            for (int i = 0; i < 16; i++) a += hv[i] * Wsf[i*16 + o];
            yv[o] = a;
        }
        if (act) {
            float4* y4 = (float4*)(y + (size_t)n * 16);
#pragma unroll
            for (int k = 0; k < 4; k++)
                y4[k] = make_float4(yv[4*k+0], yv[4*k+1], yv[4*k+2], yv[4*k+3]);
        }
        int lane = t & 63;
#pragma unroll
        for (int o = 0; o < 16; o++) {
            float a = act ? yv[o] : 0.f;
            float b = act ? yv[o]*yv[o] : 0.f;
#pragma unroll
            for (int off = 32; off > 0; off >>= 1) {
                a += __shfl_down(a, off);
                b += __shfl_down(b, off);
            }
            if (lane == 0) { red[wv][o] = a; red[wv][16 + o] = b; }
        }
        __syncthreads();
        if (t < 32) {
            float s = red[0][t] + red[1][t] + red[2][t] + red[3][t];
            atomicAdd(&bnacc[t], s);
        }
    }
}

// ---- finalize: per-node msg gather-sum + BN + tanh + add + relu + L2-normalize ----
__global__ __launch_bounds__(256) void final_kernel(
    const float* __restrict__ msgb, const int* __restrict__ elist,
    const int* __restrict__ cntp, const int* __restrict__ dst,
    const float* __restrict__ y, const float* __restrict__ bnacc,
    const float* __restrict__ gamma, const float* __restrict__ beta,
    float* __restrict__ out)
{
    int tb = blockIdx.x * 256 + threadIdx.x;
    int n = tb >> 2, c = tb & 3;
    if (n >= NN) return;

    int deg = cntp[n * CNTP];
    const float4* m4 = (const float4*)msgb;

    float ax = 0.f, ay = 0.f, az = 0.f, aw = 0.f;
    if (deg <= CAP) {
        const int* el = elist + n * CAP;
        int k = 0;
        for (; k + 4 <= deg; k += 4) {
            int e0 = el[k], e1 = el[k+1], e2 = el[k+2], e3 = el[k+3];
            float4 a0 = m4[(size_t)e0*4 + c];
            float4 a1 = m4[(size_t)e1*4 + c];
            float4 a2 = m4[(size_t)e2*4 + c];
            float4 a3 = m4[(size_t)e3*4 + c];
            ax += (a0.x + a1.x) + (a2.x + a3.x);
            ay += (a0.y + a1.y) + (a2.y + a3.y);
            az += (a0.z + a1.z) + (a2.z + a3.z);
            aw += (a0.w + a1.w) + (a2.w + a3.w);
        }
        for (; k < deg; k++) {
            int e0 = el[k];
            float4 a0 = m4[(size_t)e0*4 + c];
            ax += a0.x; ay += a0.y; az += a0.z; aw += a0.w;
        }
    } else {
        // overflow fallback: scan every edge (correctness insurance; ~never taken)
        for (int e0 = 0; e0 < NE; e0++) {
            if (dst[e0] == n) {
                float4 a0 = m4[(size_t)e0*4 + c];
                ax += a0.x; ay += a0.y; az += a0.z; aw += a0.w;
            }
        }
    }

    float4 yv4 = ((const float4*)y)[(size_t)n * 4 + c];
    float yv[4] = {yv4.x, yv4.y, yv4.z, yv4.w};
    float nb[4] = {ax, ay, az, aw};

    const float inv_n = 1.f / (float)NN;
    float z[4];
    float ss = 0.f;
#pragma unroll
    for (int r = 0; r < 4; r++) {
        int o = c * 4 + r;
        float mu  = bnacc[o] * inv_n;
        float var = bnacc[16 + o] * inv_n - mu * mu;
        float inv = rsqrtf(var + BN_EPS);
        float yy  = (yv[r] - mu) * inv * gamma[o] + beta[o];
        float tt  = tanhf(yy);
        float zz  = fmaxf(tt + nb[r], 0.f);
        z[r] = zz;
        ss += zz * zz;
    }
    // node-wide sum of squares across the 4 owning lanes (quad never crosses a wave)
    ss += __shfl_xor(ss, 1);
    ss += __shfl_xor(ss, 2);
    float nrm = sqrtf(ss);
    if (nrm == 0.f) nrm = 1.f;
    float rr = 1.f / nrm;
    *(float4*)(out + (size_t)n * 16 + c * 4) =
        make_float4(z[0]*rr, z[1]*rr, z[2]*rr, z[3]*rr);
}

extern "C" void kernel_launch(void* const* d_in, const int* in_sizes, int n_in,
                              void* d_out, int out_size, void* d_ws, size_t ws_size,
                              hipStream_t stream) {
    const float* h_neigh = (const float*)d_in[0];
    const float* h_self  = (const float*)d_in[1];
    const float* efeat   = (const float*)d_in[2];
    const int*   src     = (const int*)d_in[3];
    const int*   dst     = (const int*)d_in[4];
    const float* W_self  = (const float*)d_in[5];
    const float* gamma   = (const float*)d_in[6];
    const float* beta    = (const float*)d_in[7];
    const float* We1     = (const float*)d_in[8];
    const float* be1     = (const float*)d_in[9];
    const float* We2     = (const float*)d_in[10];
    const float* be2     = (const float*)d_in[11];
    float* out = (float*)d_out;

    char* ws = (char*)d_ws;
    float* msgb  = (float*)ws;
    int*   elist = (int*)(ws + ELIST_OFF);
    int*   cntp  = (int*)(ws + CNT_OFF);
    float* bnacc = (float*)(ws + BNACC_OFF);
    float* y     = (float*)(ws + Y_OFF);

    // zero padded counters + BN accumulators (ws poisoned 0xAA each call)
    hipMemsetAsync(ws + ZERO_OFF, 0, ZERO_BYTES, stream);

    // 1024 blocks x 256 threads (the proven R4 shell); blocks 945..1023 also do self path.
    edge_kernel<<<1024, 256, 0, stream>>>(
        h_neigh, efeat, src, dst, We1, be1, We2, be2,
        msgb, elist, cntp,
        h_self, W_self, y, bnacc);
    final_kernel<<<(NN * 4 + 255) / 256, 256, 0, stream>>>(
        msgb, elist, cntp, dst, y, bnacc, gamma, beta, out);
}